// Round 2
// baseline (472.615 us; speedup 1.0000x reference)
//
#include <hip/hip_runtime.h>
#include <hip/hip_bf16.h>

constexpr int kN = 8192;
constexpr int kD = 128;
constexpr int kV = 3;
constexpr int kNV = kV * kN;
constexpr int kNChunk = 512;             // n columns per k_main block
constexpr int kRows = 16;                // n rows per iteration (one MFMA n-subtile)
constexpr int kIters = kNChunk / kRows;  // 32
constexpr int kAccStride = 529;          // odd stride: view-rows land on distinct banks
constexpr float kLn2 = 0.6931471805599453f;
// Hc scale = (1/T)/ln2 so that MFMA dot is already in log2 domain: exp(sim/T) == exp2(dot)
constexpr float kScaleHc = 2.885390081777927f;

typedef __attribute__((ext_vector_type(8))) short bf16x8;
typedef __attribute__((ext_vector_type(4))) float floatx4;

#if __has_builtin(__builtin_amdgcn_exp2f)
#define EXP2F(x) __builtin_amdgcn_exp2f(x)
#else
#define EXP2F(x) exp2f(x)
#endif

__device__ __forceinline__ unsigned pack_bf16(float a, float b) {
    unsigned ua = __float_as_uint(a);
    unsigned ub = __float_as_uint(b);
    ua = (ua + 0x7FFFu + ((ua >> 16) & 1u)) >> 16;   // RNE round to bf16
    ub = (ub + 0x7FFFu + ((ub >> 16) & 1u)) >> 16;
    return ua | (ub << 16);
}

// Sum over the 4 quads (lanes l, l^16, l^32, l^48) without touching the LDS pipe:
// register-copy + permlane*_swap implements the butterfly in pure VALU.
__device__ __forceinline__ float quad_sum(float p) {
    float t = p;
    asm("v_permlane16_swap_b32 %0, %1" : "+v"(p), "+v"(t));  // l <-> l^16 exchange
    p += t;
    t = p;
    asm("v_permlane32_swap_b32 %0, %1" : "+v"(p), "+v"(t));  // l <-> l^32 exchange
    return p + t;
}

// One wave per row. Rows [0,kN): Hc (scale (1/T)/ln2 folded). Rows [kN, kN+kV*kN): Hv flat.
__global__ void k_normalize(const float* __restrict__ Hc, const float* __restrict__ Hv,
                            unsigned* __restrict__ HcB, unsigned* __restrict__ HvB) {
    int row  = (blockIdx.x * blockDim.x + threadIdx.x) >> 6;
    int lane = threadIdx.x & 63;
    const float* src;
    unsigned* dst;
    float extra;
    if (row < kN) { src = Hc + (size_t)row * kD; dst = HcB + (size_t)row * (kD / 2); extra = kScaleHc; }
    else {
        int r = row - kN;
        src = Hv + (size_t)r * kD; dst = HvB + (size_t)r * (kD / 2); extra = 1.0f;
    }
    float2 x = ((const float2*)src)[lane];
    float ss = x.x * x.x + x.y * x.y;
    ss += __shfl_xor(ss, 1);  ss += __shfl_xor(ss, 2);  ss += __shfl_xor(ss, 4);
    ss += __shfl_xor(ss, 8);  ss += __shfl_xor(ss, 16); ss += __shfl_xor(ss, 32);
    float inv = extra * rsqrtf(fmaxf(ss, 1e-24f));
    dst[lane] = pack_bf16(x.x * inv, x.y * inv);
}

// One wave per (v,n). Raw dot (carries 2/ln2 scale) scattered into 256 partial slots.
__global__ void k_positive(const unsigned* __restrict__ HcB, const unsigned* __restrict__ HvB,
                           float* __restrict__ pos_partial) {
    int row  = (blockIdx.x * blockDim.x + threadIdx.x) >> 6;  // v*kN + n
    int lane = threadIdx.x & 63;
    int w    = threadIdx.x >> 6;
    int n    = row & (kN - 1);
    unsigned a = HcB[(size_t)n * (kD / 2) + lane];
    unsigned b = HvB[(size_t)row * (kD / 2) + lane];
    float dot = __uint_as_float(a << 16) * __uint_as_float(b << 16)
              + __uint_as_float(a & 0xFFFF0000u) * __uint_as_float(b & 0xFFFF0000u);
    dot += __shfl_xor(dot, 1);  dot += __shfl_xor(dot, 2);  dot += __shfl_xor(dot, 4);
    dot += __shfl_xor(dot, 8);  dot += __shfl_xor(dot, 16); dot += __shfl_xor(dot, 32);
    __shared__ float acc4[4];
    if (lane == 0) acc4[w] = dot;
    __syncthreads();
    if (threadIdx.x == 0)
        atomicAdd(&pos_partial[blockIdx.x & 255], acc4[0] + acc4[1] + acc4[2] + acc4[3]);
}

// Barrier-free main loop: B-fragments read straight from L2-resident HcB (2 MB),
// S streamed into registers with depth-2 prefetch, bfrag depth-1 prefetch.
// Per-wave accum slices in LDS (plain stores, no atomics, no zero-init);
// single barrier before the block-level flush.
__launch_bounds__(256, 4)
__global__ void k_main(const unsigned* __restrict__ HcB, const unsigned* __restrict__ HvB,
                       const float* __restrict__ S, float* __restrict__ denom) {
    __shared__ float accum[4 * kV * kAccStride];   // [wave][view][n] slices

    const int tid  = threadIdx.x;
    const int w    = tid >> 6;
    const int lane = tid & 63;
    const int col  = lane & 15;
    const int quad = lane >> 4;
    const int m0b  = blockIdx.x * 64;
    const int m0w  = m0b + w * 16;
    const int nbase = blockIdx.y * kNChunk;

    // Persistent A fragments: A[m=lane&15][k=quad*8+j]
    bf16x8 afrag[kV][4];
#pragma unroll
    for (int v = 0; v < kV; ++v) {
        const short* rowp = (const short*)HvB + ((size_t)(v * kN + m0w + col)) * kD;
#pragma unroll
        for (int kk = 0; kk < 4; ++kk)
            afrag[v][kk] = *(const bf16x8*)(rowp + kk * 32 + quad * 8);
    }

    const short* hc = (const short*)HcB;
    // per-lane bases: B-fragment rows keyed by col, S row (nbase+col), cols m0w-block
    const short* hp = hc + (size_t)(nbase + col) * kD + (quad << 3);
    const float* Sp = S + (size_t)(nbase + col) * kN + m0b + (w << 4) + (quad << 2);

    // prefetch iter 0/1
    bf16x8 bfA[4];
#pragma unroll
    for (int kk = 0; kk < 4; ++kk) bfA[kk] = *(const bf16x8*)(hp + kk * 32);
    float4 sCur = *(const float4*)(Sp);
    float4 sNxt = *(const float4*)(Sp + (size_t)kRows * kN);

#pragma unroll 4
    for (int it = 0; it < kIters; ++it) {
        // issue next-iter loads (clamped re-read at the tail; L2-hot, harmless)
        const int itn = (it + 1 < kIters) ? it + 1 : it;
        const int it2 = (it + 2 < kIters) ? it + 2 : it;
        bf16x8 bfN[4];
#pragma unroll
        for (int kk = 0; kk < 4; ++kk)
            bfN[kk] = *(const bf16x8*)(hp + (size_t)itn * kRows * kD + kk * 32);
        float4 sN2 = *(const float4*)(Sp + (size_t)it2 * kRows * kN);

        floatx4 acc0 = {0.f,0.f,0.f,0.f}, acc1 = {0.f,0.f,0.f,0.f}, acc2 = {0.f,0.f,0.f,0.f};
#pragma unroll
        for (int kk = 0; kk < 4; ++kk) {
            acc0 = __builtin_amdgcn_mfma_f32_16x16x32_bf16(afrag[0][kk], bfA[kk], acc0, 0, 0, 0);
            acc1 = __builtin_amdgcn_mfma_f32_16x16x32_bf16(afrag[1][kk], bfA[kk], acc1, 0, 0, 0);
            acc2 = __builtin_amdgcn_mfma_f32_16x16x32_bf16(afrag[2][kk], bfA[kk], acc2, 0, 0, 0);
        }
        float w0 = 1.f - sCur.x, w1 = 1.f - sCur.y, w2 = 1.f - sCur.z, w3 = 1.f - sCur.w;
        float p0 = w0 * EXP2F(acc0[0]) + w1 * EXP2F(acc0[1]) + w2 * EXP2F(acc0[2]) + w3 * EXP2F(acc0[3]);
        float p1 = w0 * EXP2F(acc1[0]) + w1 * EXP2F(acc1[1]) + w2 * EXP2F(acc1[2]) + w3 * EXP2F(acc1[3]);
        float p2 = w0 * EXP2F(acc2[0]) + w1 * EXP2F(acc2[1]) + w2 * EXP2F(acc2[2]) + w3 * EXP2F(acc2[3]);
        p0 = quad_sum(p0);
        p1 = quad_sum(p1);
        p2 = quad_sum(p2);
        float val = (quad == 0) ? p0 : ((quad == 1) ? p1 : p2);
        if (quad < 3)
            accum[(w * kV + quad) * kAccStride + it * kRows + col] = val;

#pragma unroll
        for (int kk = 0; kk < 4; ++kk) bfA[kk] = bfN[kk];
        sCur = sNxt; sNxt = sN2;
    }

    __syncthreads();
    for (int i = tid; i < kV * kNChunk; i += 256) {
        int v = i >> 9, c = i & (kNChunk - 1);
        float sum = accum[(0 * kV + v) * kAccStride + c]
                  + accum[(1 * kV + v) * kAccStride + c]
                  + accum[(2 * kV + v) * kAccStride + c]
                  + accum[(3 * kV + v) * kAccStride + c];
        atomicAdd(&denom[(size_t)v * kN + nbase + c], sum);
    }
}

__global__ void k_final(const float* __restrict__ denom, const float* __restrict__ pos_partial,
                        float* __restrict__ out) {
    int idx  = blockIdx.x * 256 + threadIdx.x;   // 0..kNV-1
    int lane = threadIdx.x & 63;
    int w    = threadIdx.x >> 6;
    float val = logf(fmaxf(denom[idx], 1e-9f));
    // pos_partial carries the 2/ln2-scaled raw dot; restore natural-log domain with *ln2
    if (blockIdx.x == 0) val -= pos_partial[threadIdx.x] * kLn2;
    val += __shfl_xor(val, 1);  val += __shfl_xor(val, 2);  val += __shfl_xor(val, 4);
    val += __shfl_xor(val, 8);  val += __shfl_xor(val, 16); val += __shfl_xor(val, 32);
    __shared__ float acc4[4];
    if (lane == 0) acc4[w] = val;
    __syncthreads();
    if (threadIdx.x == 0)
        atomicAdd(out, (acc4[0] + acc4[1] + acc4[2] + acc4[3]) * (1.0f / kNV));
}

extern "C" void kernel_launch(void* const* d_in, const int* in_sizes, int n_in,
                              void* d_out, int out_size, void* d_ws, size_t ws_size,
                              hipStream_t stream) {
    const float* Hc = (const float*)d_in[0];   // [N, D] fp32
    const float* S  = (const float*)d_in[1];   // [N, N] fp32
    const float* Hv = (const float*)d_in[2];   // [V, N, D] fp32

    unsigned* HcB  = (unsigned*)d_ws;                            // 2 MB
    unsigned* HvB  = HcB + (size_t)kN * (kD / 2);                // 6 MB
    float*    den  = (float*)(HvB + (size_t)kV * kN * (kD / 2)); // kNV floats
    float*    posp = den + kNV;                                  // 256 floats
    float*    outF = (float*)d_out;

    hipMemsetAsync(den, 0, ((size_t)kNV + 256) * sizeof(float), stream);
    hipMemsetAsync(outF, 0, sizeof(float), stream);

    k_normalize<<<dim3((kN + kV * kN) / 4), 256, 0, stream>>>(Hc, Hv, HcB, HvB);
    k_positive<<<dim3(kNV / 4), 256, 0, stream>>>(HcB, HvB, posp);
    k_main<<<dim3(kN / 64, kN / kNChunk), dim3(256), 0, stream>>>(HcB, HvB, S, den);
    k_final<<<dim3(kNV / 256), dim3(256), 0, stream>>>(den, posp, outF);
}

// Round 3
// 407.901 us; speedup vs baseline: 1.1587x; 1.1587x over previous
//
#include <hip/hip_runtime.h>
#include <hip/hip_bf16.h>

constexpr int kN = 8192;
constexpr int kD = 128;
constexpr int kV = 3;
constexpr int kNV = kV * kN;
constexpr int kNChunk = 512;             // n columns per k_main block
constexpr int kNTile = 32;               // n per iteration (2 MFMA n-subtiles)
constexpr int kIters = kNChunk / kNTile; // 16
constexpr int kAccStride = 529;          // odd stride: slices land on distinct banks
constexpr float kLn2 = 0.6931471805599453f;
// Hc scale = (1/T)/ln2 so that MFMA dot is already in log2 domain: exp(sim/T) == exp2(dot)
constexpr float kScaleHc = 2.885390081777927f;

typedef __attribute__((ext_vector_type(8))) short bf16x8;
typedef __attribute__((ext_vector_type(4))) float floatx4;

#if __has_builtin(__builtin_amdgcn_exp2f)
#define EXP2F(x) __builtin_amdgcn_exp2f(x)
#else
#define EXP2F(x) exp2f(x)
#endif

__device__ __forceinline__ unsigned pack_bf16(float a, float b) {
    unsigned ua = __float_as_uint(a);
    unsigned ub = __float_as_uint(b);
    ua = (ua + 0x7FFFu + ((ua >> 16) & 1u)) >> 16;   // RNE round to bf16
    ub = (ub + 0x7FFFu + ((ub >> 16) & 1u)) >> 16;
    return ua | (ub << 16);
}

// Sum over the 4 quads (lanes l, l^16, l^32, l^48) without touching the LDS pipe:
// register-copy + permlane*_swap implements the butterfly in pure VALU.
__device__ __forceinline__ float quad_sum(float p) {
    float t = p;
    asm("v_permlane16_swap_b32 %0, %1" : "+v"(p), "+v"(t));  // l <-> l^16 exchange
    p += t;
    t = p;
    asm("v_permlane32_swap_b32 %0, %1" : "+v"(p), "+v"(t));  // l <-> l^32 exchange
    return p + t;
}

// One wave per row. Rows [0,kN): Hc (scale (1/T)/ln2 folded). Rows [kN, kN+kV*kN): Hv flat.
__global__ void k_normalize(const float* __restrict__ Hc, const float* __restrict__ Hv,
                            unsigned* __restrict__ HcB, unsigned* __restrict__ HvB) {
    int row  = (blockIdx.x * blockDim.x + threadIdx.x) >> 6;
    int lane = threadIdx.x & 63;
    const float* src;
    unsigned* dst;
    float extra;
    if (row < kN) { src = Hc + (size_t)row * kD; dst = HcB + (size_t)row * (kD / 2); extra = kScaleHc; }
    else {
        int r = row - kN;
        src = Hv + (size_t)r * kD; dst = HvB + (size_t)r * (kD / 2); extra = 1.0f;
    }
    float2 x = ((const float2*)src)[lane];
    float ss = x.x * x.x + x.y * x.y;
    ss += __shfl_xor(ss, 1);  ss += __shfl_xor(ss, 2);  ss += __shfl_xor(ss, 4);
    ss += __shfl_xor(ss, 8);  ss += __shfl_xor(ss, 16); ss += __shfl_xor(ss, 32);
    float inv = extra * rsqrtf(fmaxf(ss, 1e-24f));
    dst[lane] = pack_bf16(x.x * inv, x.y * inv);
}

// One wave per (v,n). Raw dot (carries 2/ln2 scale) scattered into 256 partial slots.
__global__ void k_positive(const unsigned* __restrict__ HcB, const unsigned* __restrict__ HvB,
                           float* __restrict__ pos_partial) {
    int row  = (blockIdx.x * blockDim.x + threadIdx.x) >> 6;  // v*kN + n
    int lane = threadIdx.x & 63;
    int w    = threadIdx.x >> 6;
    int n    = row & (kN - 1);
    unsigned a = HcB[(size_t)n * (kD / 2) + lane];
    unsigned b = HvB[(size_t)row * (kD / 2) + lane];
    float dot = __uint_as_float(a << 16) * __uint_as_float(b << 16)
              + __uint_as_float(a & 0xFFFF0000u) * __uint_as_float(b & 0xFFFF0000u);
    dot += __shfl_xor(dot, 1);  dot += __shfl_xor(dot, 2);  dot += __shfl_xor(dot, 4);
    dot += __shfl_xor(dot, 8);  dot += __shfl_xor(dot, 16); dot += __shfl_xor(dot, 32);
    __shared__ float acc4[4];
    if (lane == 0) acc4[w] = dot;
    __syncthreads();
    if (threadIdx.x == 0)
        atomicAdd(&pos_partial[blockIdx.x & 255], acc4[0] + acc4[1] + acc4[2] + acc4[3]);
}

// Double-buffered Hc LDS pipeline (round-1 structure); S streamed straight into
// per-lane registers, prefetched one iteration ahead. Denominator partials go to
// PER-WAVE LDS slices with plain stores (no LDS atomics, no zero-init); the four
// wave slices are summed once at the end-of-block flush.
__launch_bounds__(256, 3)
__global__ void k_main(const unsigned* __restrict__ HcB, const unsigned* __restrict__ HvB,
                       const float* __restrict__ S, float* __restrict__ denom) {
    __shared__ short Htile[2][kNTile * 136];          // 136-short row stride (272B, 16B aligned)
    __shared__ float accum[4 * kV * kAccStride];      // [wave][view][n] slices, plain stores

    const int tid  = threadIdx.x;
    const int w    = tid >> 6;
    const int lane = tid & 63;
    const int col  = lane & 15;
    const int quad = lane >> 4;
    const int m0b  = blockIdx.x * 64;
    const int m0w  = m0b + w * 16;
    const int nbase = blockIdx.y * kNChunk;
    const int sr = tid >> 4;      // staging row 0..15 (and +16)
    const int sc = tid & 15;      // staging 16B chunk

    // Persistent A fragments: A[m=lane&15][k=quad*8+j]
    bf16x8 afrag[kV][4];
#pragma unroll
    for (int v = 0; v < kV; ++v) {
        const short* rowp = (const short*)HvB + ((size_t)(v * kN + m0w + col)) * kD;
#pragma unroll
        for (int kk = 0; kk < 4; ++kk)
            afrag[v][kk] = *(const bf16x8*)(rowp + kk * 32 + quad * 8);
    }

    const short* hc = (const short*)HcB;
    // per-lane S base: row (nbase+col), cols m0w + quad*4 .. +3 (16B aligned)
    const float* Sp = S + (size_t)(nbase + col) * kN + m0b + (w << 4) + (quad << 2);

    // preload Hc tile 0 into LDS; prefetch iter-0 S into registers
    {
        float4 ha = *(const float4*)(hc + (size_t)(nbase + sr) * kD + sc * 8);
        float4 hb = *(const float4*)(hc + (size_t)(nbase + sr + 16) * kD + sc * 8);
        *(float4*)&Htile[0][sr * 136 + sc * 8]        = ha;
        *(float4*)&Htile[0][(sr + 16) * 136 + sc * 8] = hb;
    }
    float4 s0 = *(const float4*)(Sp);
    float4 s1 = *(const float4*)(Sp + (size_t)16 * kN);
    __syncthreads();

    for (int it = 0; it < kIters; ++it) {
        // issue next tile's loads (clamped re-read on last iter; L2-hot, harmless)
        int itn = (it + 1 < kIters) ? it + 1 : it;
        int n0n = nbase + itn * kNTile;
        float4 ha  = *(const float4*)(hc + (size_t)(n0n + sr) * kD + sc * 8);
        float4 hb  = *(const float4*)(hc + (size_t)(n0n + sr + 16) * kD + sc * 8);
        float4 s0n = *(const float4*)(Sp + (size_t)(itn * 32) * kN);
        float4 s1n = *(const float4*)(Sp + (size_t)(itn * 32 + 16) * kN);

        const int cur = it & 1;
#pragma unroll
        for (int sub = 0; sub < 2; ++sub) {
            const int nrow = sub * 16 + col;
            bf16x8 bfrag[4];
#pragma unroll
            for (int kk = 0; kk < 4; ++kk)
                bfrag[kk] = *(const bf16x8*)&Htile[cur][nrow * 136 + kk * 32 + quad * 8];
            float4 s4 = sub ? s1 : s0;

            floatx4 acc0 = {0.f,0.f,0.f,0.f}, acc1 = {0.f,0.f,0.f,0.f}, acc2 = {0.f,0.f,0.f,0.f};
#pragma unroll
            for (int kk = 0; kk < 4; ++kk) {
                acc0 = __builtin_amdgcn_mfma_f32_16x16x32_bf16(afrag[0][kk], bfrag[kk], acc0, 0, 0, 0);
                acc1 = __builtin_amdgcn_mfma_f32_16x16x32_bf16(afrag[1][kk], bfrag[kk], acc1, 0, 0, 0);
                acc2 = __builtin_amdgcn_mfma_f32_16x16x32_bf16(afrag[2][kk], bfrag[kk], acc2, 0, 0, 0);
            }
            float w0 = 1.f - s4.x, w1 = 1.f - s4.y, w2 = 1.f - s4.z, w3 = 1.f - s4.w;
            float p0 = w0 * EXP2F(acc0[0]) + w1 * EXP2F(acc0[1]) + w2 * EXP2F(acc0[2]) + w3 * EXP2F(acc0[3]);
            float p1 = w0 * EXP2F(acc1[0]) + w1 * EXP2F(acc1[1]) + w2 * EXP2F(acc1[2]) + w3 * EXP2F(acc1[3]);
            float p2 = w0 * EXP2F(acc2[0]) + w1 * EXP2F(acc2[1]) + w2 * EXP2F(acc2[2]) + w3 * EXP2F(acc2[3]);
            p0 = quad_sum(p0);
            p1 = quad_sum(p1);
            p2 = quad_sum(p2);
            float val = (quad == 0) ? p0 : ((quad == 1) ? p1 : p2);
            if (quad < 3)
                accum[(w * kV + quad) * kAccStride + it * kNTile + sub * 16 + col] = val;
        }

        s0 = s0n; s1 = s1n;
        const int nxt = cur ^ 1;
        *(float4*)&Htile[nxt][sr * 136 + sc * 8]        = ha;
        *(float4*)&Htile[nxt][(sr + 16) * 136 + sc * 8] = hb;
        __syncthreads();
    }

    for (int i = tid; i < kV * kNChunk; i += 256) {
        int v = i >> 9, c = i & (kNChunk - 1);
        float sum = accum[(0 * kV + v) * kAccStride + c]
                  + accum[(1 * kV + v) * kAccStride + c]
                  + accum[(2 * kV + v) * kAccStride + c]
                  + accum[(3 * kV + v) * kAccStride + c];
        atomicAdd(&denom[(size_t)v * kN + nbase + c], sum);
    }
}

__global__ void k_final(const float* __restrict__ denom, const float* __restrict__ pos_partial,
                        float* __restrict__ out) {
    int idx  = blockIdx.x * 256 + threadIdx.x;   // 0..kNV-1
    int lane = threadIdx.x & 63;
    int w    = threadIdx.x >> 6;
    float val = logf(fmaxf(denom[idx], 1e-9f));
    // pos_partial carries the 2/ln2-scaled raw dot; restore natural-log domain with *ln2
    if (blockIdx.x == 0) val -= pos_partial[threadIdx.x] * kLn2;
    val += __shfl_xor(val, 1);  val += __shfl_xor(val, 2);  val += __shfl_xor(val, 4);
    val += __shfl_xor(val, 8);  val += __shfl_xor(val, 16); val += __shfl_xor(val, 32);
    __shared__ float acc4[4];
    if (lane == 0) acc4[w] = val;
    __syncthreads();
    if (threadIdx.x == 0)
        atomicAdd(out, (acc4[0] + acc4[1] + acc4[2] + acc4[3]) * (1.0f / kNV));
}

extern "C" void kernel_launch(void* const* d_in, const int* in_sizes, int n_in,
                              void* d_out, int out_size, void* d_ws, size_t ws_size,
                              hipStream_t stream) {
    const float* Hc = (const float*)d_in[0];   // [N, D] fp32
    const float* S  = (const float*)d_in[1];   // [N, N] fp32
    const float* Hv = (const float*)d_in[2];   // [V, N, D] fp32

    unsigned* HcB  = (unsigned*)d_ws;                            // 2 MB
    unsigned* HvB  = HcB + (size_t)kN * (kD / 2);                // 6 MB
    float*    den  = (float*)(HvB + (size_t)kV * kN * (kD / 2)); // kNV floats
    float*    posp = den + kNV;                                  // 256 floats
    float*    outF = (float*)d_out;

    hipMemsetAsync(den, 0, ((size_t)kNV + 256) * sizeof(float), stream);
    hipMemsetAsync(outF, 0, sizeof(float), stream);

    k_normalize<<<dim3((kN + kV * kN) / 4), 256, 0, stream>>>(Hc, Hv, HcB, HvB);
    k_positive<<<dim3(kNV / 4), 256, 0, stream>>>(HcB, HvB, posp);
    k_main<<<dim3(kN / 64, kN / kNChunk), dim3(256), 0, stream>>>(HcB, HvB, S, den);
    k_final<<<dim3(kNV / 256), dim3(256), 0, stream>>>(den, posp, outF);
}

// Round 4
// 397.526 us; speedup vs baseline: 1.1889x; 1.0261x over previous
//
#include <hip/hip_runtime.h>
#include <hip/hip_bf16.h>

constexpr int kN = 8192;
constexpr int kD = 128;
constexpr int kV = 3;
constexpr int kNV = kV * kN;
constexpr int kNChunk = 512;             // n columns per k_main block
constexpr int kMTile = 128;              // m rows per block = 4 waves x 32
constexpr int kRows = 32;                // n rows per iteration (one 32x32 MFMA n-tile)
constexpr int kIters = kNChunk / kRows;  // 16
constexpr int kAccStride = 520;          // slice stride (512 + 8 pad)
constexpr float kLn2 = 0.6931471805599453f;
// Hc scale = (1/T)/ln2 so that MFMA dot is already in log2 domain: exp(sim/T) == exp2(dot)
constexpr float kScaleHc = 2.885390081777927f;

typedef __attribute__((ext_vector_type(8))) short bf16x8;
typedef __attribute__((ext_vector_type(16))) float floatx16;

#if __has_builtin(__builtin_amdgcn_exp2f)
#define EXP2F(x) __builtin_amdgcn_exp2f(x)
#else
#define EXP2F(x) exp2f(x)
#endif

__device__ __forceinline__ unsigned pack_bf16(float a, float b) {
    unsigned ua = __float_as_uint(a);
    unsigned ub = __float_as_uint(b);
    ua = (ua + 0x7FFFu + ((ua >> 16) & 1u)) >> 16;   // RNE round to bf16
    ub = (ub + 0x7FFFu + ((ub >> 16) & 1u)) >> 16;
    return ua | (ub << 16);
}

// Sum lane l with lane l^32 (pure VALU, no LDS pipe): register copy + permlane32_swap.
__device__ __forceinline__ float half_sum(float p) {
    float t = p;
    asm("v_permlane32_swap_b32 %0, %1" : "+v"(p), "+v"(t));
    return p + t;
}

// One wave per row. Rows [0,kN): Hc (scale (1/T)/ln2 folded). Rows [kN, kN+kV*kN): Hv flat.
__global__ void k_normalize(const float* __restrict__ Hc, const float* __restrict__ Hv,
                            unsigned* __restrict__ HcB, unsigned* __restrict__ HvB) {
    int row  = (blockIdx.x * blockDim.x + threadIdx.x) >> 6;
    int lane = threadIdx.x & 63;
    const float* src;
    unsigned* dst;
    float extra;
    if (row < kN) { src = Hc + (size_t)row * kD; dst = HcB + (size_t)row * (kD / 2); extra = kScaleHc; }
    else {
        int r = row - kN;
        src = Hv + (size_t)r * kD; dst = HvB + (size_t)r * (kD / 2); extra = 1.0f;
    }
    float2 x = ((const float2*)src)[lane];
    float ss = x.x * x.x + x.y * x.y;
    ss += __shfl_xor(ss, 1);  ss += __shfl_xor(ss, 2);  ss += __shfl_xor(ss, 4);
    ss += __shfl_xor(ss, 8);  ss += __shfl_xor(ss, 16); ss += __shfl_xor(ss, 32);
    float inv = extra * rsqrtf(fmaxf(ss, 1e-24f));
    dst[lane] = pack_bf16(x.x * inv, x.y * inv);
}

// One wave per (v,n). Raw dot (carries 2/ln2 scale) scattered into 256 partial slots.
__global__ void k_positive(const unsigned* __restrict__ HcB, const unsigned* __restrict__ HvB,
                           float* __restrict__ pos_partial) {
    int row  = (blockIdx.x * blockDim.x + threadIdx.x) >> 6;  // v*kN + n
    int lane = threadIdx.x & 63;
    int w    = threadIdx.x >> 6;
    int n    = row & (kN - 1);
    unsigned a = HcB[(size_t)n * (kD / 2) + lane];
    unsigned b = HvB[(size_t)row * (kD / 2) + lane];
    float dot = __uint_as_float(a << 16) * __uint_as_float(b << 16)
              + __uint_as_float(a & 0xFFFF0000u) * __uint_as_float(b & 0xFFFF0000u);
    dot += __shfl_xor(dot, 1);  dot += __shfl_xor(dot, 2);  dot += __shfl_xor(dot, 4);
    dot += __shfl_xor(dot, 8);  dot += __shfl_xor(dot, 16); dot += __shfl_xor(dot, 32);
    __shared__ float acc4[4];
    if (lane == 0) acc4[w] = dot;
    __syncthreads();
    if (threadIdx.x == 0)
        atomicAdd(&pos_partial[blockIdx.x & 255], acc4[0] + acc4[1] + acc4[2] + acc4[3]);
}

// 32x32x16 MFMA main loop: each wave owns 32 m-rows (block = 128 m), persistent
// Hv A-fragments (3 views x 8 k-slices) in registers. Hc tile (32 n-rows) double-
// buffered in LDS; each 1KB B-fragment now feeds m=32 (2x the B-reuse of 16x16).
// 16 of the 32 m-values reduce IN-LANE over the 16 accumulator regs; one
// permlane32_swap finishes the m-sum. S streamed into registers (4 float4/lane),
// prefetched one iteration ahead. Per-wave accum LDS slices, plain stores.
__launch_bounds__(256, 2)
__global__ void k_main(const unsigned* __restrict__ HcB, const unsigned* __restrict__ HvB,
                       const float* __restrict__ S, float* __restrict__ denom) {
    __shared__ short Htile[2][kRows * 136];          // 136-short row stride (272B, 16B aligned)
    __shared__ float accum[4 * kV * kAccStride];     // [wave][view][n] slices, plain stores

    const int tid  = threadIdx.x;
    const int w    = tid >> 6;
    const int lane = tid & 63;
    const int l31  = lane & 31;    // A row (m) / B col (n) / C col (n)
    const int kh   = lane >> 5;    // k-half selector
    const int m0b  = blockIdx.x * kMTile;
    const int m0w  = m0b + w * 32;
    const int nbase = blockIdx.y * kNChunk;
    const int sr = tid >> 4;      // staging row 0..15 (and +16)
    const int sc = tid & 15;      // staging 16B chunk

    // Persistent A fragments: A[m = l31][k = ks*16 + kh*8 + j]
    bf16x8 afrag[kV][8];
#pragma unroll
    for (int v = 0; v < kV; ++v) {
        const short* rowp = (const short*)HvB + ((size_t)(v * kN + m0w + l31)) * kD + kh * 8;
#pragma unroll
        for (int ks = 0; ks < 8; ++ks)
            afrag[v][ks] = *(const bf16x8*)(rowp + ks * 16);
    }

    const short* hc = (const short*)HcB;
    // per-lane S base: row (nbase + l31), cols m0w + kh*4 (+ g*8 per group)
    const float* Sp = S + (size_t)(nbase + l31) * kN + m0w + (kh << 2);

    // preload Hc tile 0 into LDS; prefetch iter-0 S into registers
    {
        float4 ha = *(const float4*)(hc + (size_t)(nbase + sr) * kD + sc * 8);
        float4 hb = *(const float4*)(hc + (size_t)(nbase + sr + 16) * kD + sc * 8);
        *(float4*)&Htile[0][sr * 136 + sc * 8]        = ha;
        *(float4*)&Htile[0][(sr + 16) * 136 + sc * 8] = hb;
    }
    float4 sg0 = *(const float4*)(Sp);
    float4 sg1 = *(const float4*)(Sp + 8);
    float4 sg2 = *(const float4*)(Sp + 16);
    float4 sg3 = *(const float4*)(Sp + 24);
    __syncthreads();

    for (int it = 0; it < kIters; ++it) {
        // issue next tile's loads (clamped re-read on last iter; L2-hot, harmless)
        int itn = (it + 1 < kIters) ? it + 1 : it;
        int n0n = nbase + itn * kRows;
        float4 ha  = *(const float4*)(hc + (size_t)(n0n + sr) * kD + sc * 8);
        float4 hb  = *(const float4*)(hc + (size_t)(n0n + sr + 16) * kD + sc * 8);
        const float* Spn = Sp + (size_t)(itn * kRows) * kN;
        float4 sn0 = *(const float4*)(Spn);
        float4 sn1 = *(const float4*)(Spn + 8);
        float4 sn2 = *(const float4*)(Spn + 16);
        float4 sn3 = *(const float4*)(Spn + 24);

        const int cur = it & 1;
        floatx16 a0 = {0.f}, a1 = {0.f}, a2 = {0.f};
#pragma unroll
        for (int ks = 0; ks < 8; ++ks) {
            bf16x8 bfrag = *(const bf16x8*)&Htile[cur][l31 * 136 + ks * 16 + kh * 8];
            a0 = __builtin_amdgcn_mfma_f32_32x32x16_bf16(afrag[0][ks], bfrag, a0, 0, 0, 0);
            a1 = __builtin_amdgcn_mfma_f32_32x32x16_bf16(afrag[1][ks], bfrag, a1, 0, 0, 0);
            a2 = __builtin_amdgcn_mfma_f32_32x32x16_bf16(afrag[2][ks], bfrag, a2, 0, 0, 0);
        }

        // weighted in-lane m-reduction: acc reg r covers m = 8*(r>>2) + 4*kh + (r&3)
        float p0 = 0.f, p1 = 0.f, p2 = 0.f;
#pragma unroll
        for (int g = 0; g < 4; ++g) {
            float4 s4 = (g == 0) ? sg0 : (g == 1) ? sg1 : (g == 2) ? sg2 : sg3;
            float w0 = 1.f - s4.x, w1 = 1.f - s4.y, w2 = 1.f - s4.z, w3 = 1.f - s4.w;
            p0 += w0 * EXP2F(a0[g*4+0]) + w1 * EXP2F(a0[g*4+1]) + w2 * EXP2F(a0[g*4+2]) + w3 * EXP2F(a0[g*4+3]);
            p1 += w0 * EXP2F(a1[g*4+0]) + w1 * EXP2F(a1[g*4+1]) + w2 * EXP2F(a1[g*4+2]) + w3 * EXP2F(a1[g*4+3]);
            p2 += w0 * EXP2F(a2[g*4+0]) + w1 * EXP2F(a2[g*4+1]) + w2 * EXP2F(a2[g*4+2]) + w3 * EXP2F(a2[g*4+3]);
        }
        p0 = half_sum(p0);
        p1 = half_sum(p1);
        p2 = half_sum(p2);
        if (lane < 32) {
            float* slot = &accum[(w * kV) * kAccStride + it * kRows + l31];
            slot[0 * kAccStride] = p0;
            slot[1 * kAccStride] = p1;
            slot[2 * kAccStride] = p2;
        }

        sg0 = sn0; sg1 = sn1; sg2 = sn2; sg3 = sn3;
        const int nxt = cur ^ 1;
        *(float4*)&Htile[nxt][sr * 136 + sc * 8]        = ha;
        *(float4*)&Htile[nxt][(sr + 16) * 136 + sc * 8] = hb;
        __syncthreads();
    }

    for (int i = tid; i < kV * kNChunk; i += 256) {
        int v = i >> 9, c = i & (kNChunk - 1);
        float sum = accum[(0 * kV + v) * kAccStride + c]
                  + accum[(1 * kV + v) * kAccStride + c]
                  + accum[(2 * kV + v) * kAccStride + c]
                  + accum[(3 * kV + v) * kAccStride + c];
        atomicAdd(&denom[(size_t)v * kN + nbase + c], sum);
    }
}

__global__ void k_final(const float* __restrict__ denom, const float* __restrict__ pos_partial,
                        float* __restrict__ out) {
    int idx  = blockIdx.x * 256 + threadIdx.x;   // 0..kNV-1
    int lane = threadIdx.x & 63;
    int w    = threadIdx.x >> 6;
    float val = logf(fmaxf(denom[idx], 1e-9f));
    // pos_partial carries the 2/ln2-scaled raw dot; restore natural-log domain with *ln2
    if (blockIdx.x == 0) val -= pos_partial[threadIdx.x] * kLn2;
    val += __shfl_xor(val, 1);  val += __shfl_xor(val, 2);  val += __shfl_xor(val, 4);
    val += __shfl_xor(val, 8);  val += __shfl_xor(val, 16); val += __shfl_xor(val, 32);
    __shared__ float acc4[4];
    if (lane == 0) acc4[w] = val;
    __syncthreads();
    if (threadIdx.x == 0)
        atomicAdd(out, (acc4[0] + acc4[1] + acc4[2] + acc4[3]) * (1.0f / kNV));
}

extern "C" void kernel_launch(void* const* d_in, const int* in_sizes, int n_in,
                              void* d_out, int out_size, void* d_ws, size_t ws_size,
                              hipStream_t stream) {
    const float* Hc = (const float*)d_in[0];   // [N, D] fp32
    const float* S  = (const float*)d_in[1];   // [N, N] fp32
    const float* Hv = (const float*)d_in[2];   // [V, N, D] fp32

    unsigned* HcB  = (unsigned*)d_ws;                            // 2 MB
    unsigned* HvB  = HcB + (size_t)kN * (kD / 2);                // 6 MB
    float*    den  = (float*)(HvB + (size_t)kV * kN * (kD / 2)); // kNV floats
    float*    posp = den + kNV;                                  // 256 floats
    float*    outF = (float*)d_out;

    hipMemsetAsync(den, 0, ((size_t)kNV + 256) * sizeof(float), stream);
    hipMemsetAsync(outF, 0, sizeof(float), stream);

    k_normalize<<<dim3((kN + kV * kN) / 4), 256, 0, stream>>>(Hc, Hv, HcB, HvB);
    k_positive<<<dim3(kNV / 4), 256, 0, stream>>>(HcB, HvB, posp);
    k_main<<<dim3(kN / kMTile, kN / kNChunk), dim3(256), 0, stream>>>(HcB, HvB, S, den);
    k_final<<<dim3(kNV / 256), dim3(256), 0, stream>>>(den, posp, outF);
}